// Round 2
// baseline (107.911 us; speedup 1.0000x reference)
//
#include <hip/hip_runtime.h>

#define NQ 18
#define QDIM (1 << NQ)      // 262144
#define NBATCH 8
#define NLAYERS 4

// complex butterfly: a' = c*a + (-i s)*b ; b' = (-i s)*a + c*b
__device__ __forceinline__ void bfly(float2& a, float2& b, float c, float s) {
  float nax = fmaf(c, a.x, s * b.y);
  float nay = fmaf(c, a.y, -s * b.x);
  float nbx = fmaf(c, b.x, s * a.y);
  float nby = fmaf(c, b.y, -s * a.x);
  a.x = nax; a.y = nay; b.x = nbx; b.y = nby;
}

// butterfly across in-register slot bit (xor mask m on vi), 16 slots
__device__ __forceinline__ void regstage(float2* v, int m, float c, float s) {
#pragma unroll
  for (int vi = 0; vi < 16; ++vi)
    if (!(vi & m)) bfly(v[vi], v[vi | m], c, s);
}

// butterfly across a lane bit via shfl_xor; new = c*mine + (-i s)*other
__device__ __forceinline__ void shflstage(float2* v, int mask, float c, float s) {
#pragma unroll
  for (int k = 0; k < 16; ++k) {
    float ox = __shfl_xor(v[k].x, mask, 64);
    float oy = __shfl_xor(v[k].y, mask, 64);
    float nx = fmaf(c, v[k].x, s * oy);
    float ny = fmaf(c, v[k].y, -s * ox);
    v[k].x = nx; v[k].y = ny;
  }
}

__device__ __forceinline__ void pmul(float2& a, float2 p) {  // a *= (p.x + i p.y)
  float nx = a.x * p.x - a.y * p.y;
  float ny = a.x * p.y + a.y * p.x;
  a.x = nx; a.y = ny;
}

// A-tile (per wave, 1024 contiguous elems): e = g<<10 | r<<7 | lane<<1 | c
//   vi = 2r + c : e bit0 = c = vi bit0 ; e bits 7..9 = r = vi bits 1..3 ;
//   e bits 1..6 = lane. mixLow covers e bits 0..9.
__device__ __forceinline__ void mixLow(float2* v, float c, float s) {
  regstage(v, 1, c, s);
  shflstage(v, 1, c, s);  shflstage(v, 2, c, s);  shflstage(v, 4, c, s);
  shflstage(v, 8, c, s);  shflstage(v, 16, c, s); shflstage(v, 32, c, s);
  regstage(v, 2, c, s);   regstage(v, 4, c, s);   regstage(v, 8, c, s);
}

// B-comb (per wave, 1024 elems): e = r<<15 | Lhi<<10 | g<<2 | l0<<1 | c
//   Lhi = lane>>1 (5 bits -> e bits 10..14), r = vi bits 1..3 -> e bits 15..17.
// mixHigh covers e bits 10..17 (8 bits).
__device__ __forceinline__ void mixHigh(float2* v, float c, float s) {
  shflstage(v, 2, c, s);  shflstage(v, 4, c, s);  shflstage(v, 8, c, s);
  shflstage(v, 16, c, s); shflstage(v, 32, c, s);
  regstage(v, 2, c, s);   regstage(v, 4, c, s);   regstage(v, 8, c, s);
}

// one tiny block: zero out[8] + extract 8x18 adjacency bit-masks
__global__ void k_pre(const float* __restrict__ adj, unsigned* __restrict__ masks,
                      float* __restrict__ out) {
  const int tid = threadIdx.x;
  if (tid < NBATCH) out[tid] = 0.f;
  if (tid < NBATCH * NQ) {
    const int b = tid / NQ, u = tid % NQ;
    unsigned m = 0;
    const float* row = adj + ((size_t)b * NQ + u) * NQ;
    for (int vv = u + 1; vv < NQ; ++vv)
      if (row[vv] > 0.5f) m |= 1u << (NQ - 1 - vv);
    masks[tid] = m;
  }
}

// MODE 0: state = e^{-i hp}/sqrt(dim), store hp u8, mixLow(beta[t0])
// MODE 1: load, mixLow(beta[t0]), phase, mixLow(beta[t0+1]), store
// MODE 2: load, mixLow(beta[t0]), energy -> atomicAdd(out[b])
template <int MODE>
__global__ __launch_bounds__(256)
void k_passA(const float* __restrict__ betas, const unsigned* __restrict__ masks,
             unsigned char* __restrict__ hp8, float2* __restrict__ state,
             float* __restrict__ out, int t0) {
  __shared__ float2 ptab[160];
  __shared__ unsigned smask[NQ];
  const int tid = threadIdx.x;
  if (MODE != 2) {
    if (tid < 160) {
      float s, c; sincosf((float)tid, &s, &c);
      ptab[tid] = make_float2(c, -s);
    }
    if (MODE == 0 && tid < NQ)
      smask[tid] = masks[(((blockIdx.x * 4) >> 8) * NQ) + tid];
    __syncthreads();
  }
  const int T = blockIdx.x * 4 + (tid >> 6);
  const int b = T >> 8;           // 256 waves per batch
  const int g = T & 255;
  const int lane = tid & 63;
  const size_t bbase = (size_t)b * QDIM;
  const int tbase = g << 10;

  float2 v[16];
  const float cs0 = cosf(betas[b * NLAYERS + t0]);
  const float sn0 = sinf(betas[b * NLAYERS + t0]);

  if (MODE == 0) {
    const float inv = 0.001953125f;  // 1/512
#pragma unroll
    for (int r = 0; r < 8; ++r) {
      const int off = tbase + (r << 7) + (lane << 1);
      const unsigned d0 = (unsigned)off, d1 = d0 + 1u;
      int hp0 = 0, hp1 = 0;
#pragma unroll
      for (int u = 0; u < NQ; ++u) {
        const unsigned mu = smask[u];
        const unsigned f0 = (d0 >> (NQ - 1 - u)) & 1u;
        const unsigned f1 = (d1 >> (NQ - 1 - u)) & 1u;
        hp0 += __popc(mu & (d0 ^ (0u - f0)));
        hp1 += __popc(mu & (d1 ^ (0u - f1)));
      }
      *(unsigned short*)(hp8 + bbase + off) = (unsigned short)(hp0 | (hp1 << 8));
      const float2 p0 = ptab[hp0], p1 = ptab[hp1];
      v[2 * r].x = p0.x * inv;     v[2 * r].y = p0.y * inv;
      v[2 * r + 1].x = p1.x * inv; v[2 * r + 1].y = p1.y * inv;
    }
  } else {
#pragma unroll
    for (int r = 0; r < 8; ++r) {
      const float4 t = *(const float4*)&state[bbase + tbase + (r << 7) + (lane << 1)];
      v[2 * r].x = t.x; v[2 * r].y = t.y;
      v[2 * r + 1].x = t.z; v[2 * r + 1].y = t.w;
    }
  }

  mixLow(v, cs0, sn0);

  if (MODE == 1) {
    const float cs1 = cosf(betas[b * NLAYERS + t0 + 1]);
    const float sn1 = sinf(betas[b * NLAYERS + t0 + 1]);
#pragma unroll
    for (int r = 0; r < 8; ++r) {
      const unsigned short h2 =
          *(const unsigned short*)(hp8 + bbase + tbase + (r << 7) + (lane << 1));
      pmul(v[2 * r], ptab[h2 & 255]);
      pmul(v[2 * r + 1], ptab[h2 >> 8]);
    }
    mixLow(v, cs1, sn1);
  }

  if (MODE == 2) {
    float acc = 0.f;
#pragma unroll
    for (int r = 0; r < 8; ++r) {
      const unsigned short h2 =
          *(const unsigned short*)(hp8 + bbase + tbase + (r << 7) + (lane << 1));
      const float2 a = v[2 * r], bb = v[2 * r + 1];
      acc += (a.x * a.x + a.y * a.y) * (float)(h2 & 255);
      acc += (bb.x * bb.x + bb.y * bb.y) * (float)(h2 >> 8);
    }
#pragma unroll
    for (int m = 1; m <= 32; m <<= 1) acc += __shfl_xor(acc, m, 64);
    if (lane == 0) atomicAdd(out + b, acc);
  } else {
#pragma unroll
    for (int r = 0; r < 8; ++r) {
      float4 t;
      t.x = v[2 * r].x; t.y = v[2 * r].y;
      t.z = v[2 * r + 1].x; t.w = v[2 * r + 1].y;
      *(float4*)&state[bbase + tbase + (r << 7) + (lane << 1)] = t;
    }
  }
}

// B pass: load comb tile, mixHigh(beta[t0]), phase(t0+1), mixHigh(beta[t0+1]), store
__global__ __launch_bounds__(256)
void k_passB(const float* __restrict__ betas, const unsigned char* __restrict__ hp8,
             float2* __restrict__ state, int t0) {
  __shared__ float2 ptab[160];
  const int tid = threadIdx.x;
  if (tid < 160) {
    float s, c; sincosf((float)tid, &s, &c);
    ptab[tid] = make_float2(c, -s);
  }
  __syncthreads();
  const int T = blockIdx.x * 4 + (tid >> 6);
  const int b = T >> 8;
  const int g = T & 255;
  const int lane = tid & 63;
  const size_t bbase = (size_t)b * QDIM;
  const int Lhi = lane >> 1;
  const int l0 = lane & 1;
  const int gpart = (g << 2) | (l0 << 1);

  float2 v[16];
  const float cs0 = cosf(betas[b * NLAYERS + t0]);
  const float sn0 = sinf(betas[b * NLAYERS + t0]);
  const float cs1 = cosf(betas[b * NLAYERS + t0 + 1]);
  const float sn1 = sinf(betas[b * NLAYERS + t0 + 1]);

#pragma unroll
  for (int r = 0; r < 8; ++r) {
    const int off = (r << 15) | (Lhi << 10) | gpart;
    const float4 t = *(const float4*)&state[bbase + off];
    v[2 * r].x = t.x; v[2 * r].y = t.y;
    v[2 * r + 1].x = t.z; v[2 * r + 1].y = t.w;
  }

  mixHigh(v, cs0, sn0);

#pragma unroll
  for (int r = 0; r < 8; ++r) {
    const int off = (r << 15) | (Lhi << 10) | gpart;
    const unsigned short h2 = *(const unsigned short*)(hp8 + bbase + off);
    pmul(v[2 * r], ptab[h2 & 255]);
    pmul(v[2 * r + 1], ptab[h2 >> 8]);
  }

  mixHigh(v, cs1, sn1);

#pragma unroll
  for (int r = 0; r < 8; ++r) {
    const int off = (r << 15) | (Lhi << 10) | gpart;
    float4 t;
    t.x = v[2 * r].x; t.y = v[2 * r].y;
    t.z = v[2 * r + 1].x; t.w = v[2 * r + 1].y;
    *(float4*)&state[bbase + off] = t;
  }
}

extern "C" void kernel_launch(void* const* d_in, const int* in_sizes, int n_in,
                              void* d_out, int out_size, void* d_ws, size_t ws_size,
                              hipStream_t stream) {
  const float* betas = (const float*)d_in[0];  // [8][4]
  const float* adj   = (const float*)d_in[1];  // [8][18][18]
  float* out = (float*)d_out;                  // [8] float32
  char* ws = (char*)d_ws;
  float2* state = (float2*)ws;                                                        // 16 MB
  unsigned char* hp8 = (unsigned char*)(ws + (size_t)NBATCH * QDIM * sizeof(float2)); // 2 MB
  unsigned* masks = (unsigned*)(ws + (size_t)NBATCH * QDIM * (sizeof(float2) + 1));

  k_pre<<<1, 192, 0, stream>>>(adj, masks, out);

  dim3 grid(512), blk(256);
  // P1: D1 + M1.low          P2: M1.high, D2, M2.high
  // P3: M2.low, D3, M3.low   P4: M3.high, D4, M4.high
  // P5: M4.low + energy
  k_passA<0><<<grid, blk, 0, stream>>>(betas, masks, hp8, state, out, 0);
  k_passB<<<grid, blk, 0, stream>>>(betas, hp8, state, 0);
  k_passA<1><<<grid, blk, 0, stream>>>(betas, masks, hp8, state, out, 1);
  k_passB<<<grid, blk, 0, stream>>>(betas, hp8, state, 2);
  k_passA<2><<<grid, blk, 0, stream>>>(betas, masks, hp8, state, out, 3);
}

// Round 3
// 77.338 us; speedup vs baseline: 1.3953x; 1.3953x over previous
//
#include <hip/hip_runtime.h>

#define NQ 18
#define QDIM (1 << NQ)      // 262144
#define NBATCH 8
#define NLAYERS 4

// complex butterfly: a' = c*a + (-i s)*b ; b' = (-i s)*a + c*b
__device__ __forceinline__ void bfly(float2& a, float2& b, float c, float s) {
  float nax = fmaf(c, a.x,  s * b.y);
  float nay = fmaf(c, a.y, -s * b.x);
  float nbx = fmaf(c, b.x,  s * a.y);
  float nby = fmaf(c, b.y, -s * a.x);
  a = make_float2(nax, nay); b = make_float2(nbx, nby);
}

// butterfly across reg-slot bit m within 8-slot array
__device__ __forceinline__ void regstage8(float2* v, int m, float c, float s) {
#pragma unroll
  for (int i = 0; i < 8; ++i)
    if (!(i & m)) bfly(v[i], v[i | m], c, s);
}

// butterfly across a lane bit via shfl_xor: new = c*mine + (-i s)*other
__device__ __forceinline__ void shflstage8(float2* v, int mask, float c, float s) {
#pragma unroll
  for (int k = 0; k < 8; ++k) {
    float ox = __shfl_xor(v[k].x, mask, 64);
    float oy = __shfl_xor(v[k].y, mask, 64);
    v[k] = make_float2(fmaf(c, v[k].x,  s * oy),
                       fmaf(c, v[k].y, -s * ox));
  }
}

__device__ __forceinline__ void pmul(float2& a, float2 p) {  // a *= (p.x + i p.y)
  a = make_float2(a.x * p.x - a.y * p.y, a.x * p.y + a.y * p.x);
}

// XOR-swizzle for the A-pass LDS tile: flip byte bits 3-5 by byte bits 9-11.
// Involution (source bits 9-11 disjoint from target 3-5); applied on BOTH sides.
__device__ __forceinline__ int swzA(int byte) { return byte ^ (((byte >> 9) & 7) << 3); }

// ---------------- A-pass: mixes over element bits 0..11 -----------------
// Block: 512 threads, 4096 consecutive elems (bits 0-11), blk = (b, bits 12-17).
// partition1: elem = tid<<3 | j   (reg j = bits 0-2, lane = bits 3-8, wave = 9-11)
// partition2: elem = r<<9 | tid   (reg r = bits 9-11)
// MODE 0: init (hp + phase + 1/sqrt(dim)), mix(t0).low, store   [also zeroes out]
// MODE 1: load, mix(t0).low, phase, mix(t0+1).low, store
// MODE 2: load, mix(t0).low, energy -> atomicAdd(out[b])
template <int MODE>
__global__ __launch_bounds__(512)
void k_low(const float* __restrict__ betas, const float* __restrict__ adj,
           unsigned char* __restrict__ hp8, float2* __restrict__ state,
           float* __restrict__ out, int t0) {
  __shared__ float2 lds[4096];      // 32 KB
  __shared__ float2 ptab[160];
  __shared__ unsigned smask[NQ];
  __shared__ float wsum[8];

  const int tid  = threadIdx.x;     // 0..511
  const int lane = tid & 63;
  const int w    = tid >> 6;        // 0..7
  const int b    = blockIdx.x >> 6;
  const int blk6 = blockIdx.x & 63; // element bits 12-17
  const size_t bb = (size_t)b << NQ;
  const int lbase = blk6 << 12;     // batch-local base of this block's 4096 elems

  if (MODE != 2 && tid < 160) {
    float s, c; sincosf((float)tid, &s, &c);
    ptab[tid] = make_float2(c, -s);
  }
  if (MODE == 0) {
    if (tid < NQ) {
      unsigned m = 0;
      const float* row = adj + ((size_t)b * NQ + tid) * NQ;
      for (int v2 = tid + 1; v2 < NQ; ++v2)
        if (row[v2] > 0.5f) m |= 1u << (NQ - 1 - v2);
      smask[tid] = m;
    }
    if (blk6 == 0 && tid == 0) out[b] = 0.f;  // P1 completes before P5 launches
  }
  if (MODE != 2) __syncthreads();

  const float beta0 = betas[b * NLAYERS + t0];
  const float c0 = cosf(beta0), s0 = sinf(beta0);
  float2 v[8];

  if (MODE == 0) {
    const float inv = 0.001953125f;  // 1/512
    unsigned plo = 0, phi = 0;
#pragma unroll
    for (int j = 0; j < 8; ++j) {
      const unsigned d = (unsigned)(lbase | (tid << 3) | j);
      int hp = 0;
#pragma unroll
      for (int u = 0; u < NQ; ++u) {
        const unsigned f = (d >> (NQ - 1 - u)) & 1u;
        hp += __popc(smask[u] & (d ^ (0u - f)));
      }
      if (j < 4) plo |= (unsigned)hp << (8 * j);
      else       phi |= (unsigned)hp << (8 * (j - 4));
      const float2 p = ptab[hp];
      v[j] = make_float2(p.x * inv, p.y * inv);
    }
    *(uint2*)(hp8 + bb + (size_t)(lbase | (tid << 3))) = make_uint2(plo, phi);
  } else {
    const float4* gsrc = (const float4*)(state + bb + lbase + (tid << 3));
#pragma unroll
    for (int j2 = 0; j2 < 4; ++j2) {
      const float4 t4 = gsrc[j2];
      v[2 * j2]     = make_float2(t4.x, t4.y);
      v[2 * j2 + 1] = make_float2(t4.z, t4.w);
    }
  }

  // ---- mix(t0) over bits 0-8 ----
  regstage8(v, 1, c0, s0); regstage8(v, 2, c0, s0); regstage8(v, 4, c0, s0);
  shflstage8(v, 1, c0, s0);  shflstage8(v, 2, c0, s0);  shflstage8(v, 4, c0, s0);
  shflstage8(v, 8, c0, s0);  shflstage8(v, 16, c0, s0); shflstage8(v, 32, c0, s0);

  // ---- swap to partition2 ----
  char* L = (char*)lds;
#pragma unroll
  for (int j = 0; j < 8; ++j)
    *(float2*)(L + swzA((tid << 6) + (j << 3))) = v[j];
  __syncthreads();
#pragma unroll
  for (int r = 0; r < 8; ++r)
    v[r] = *(const float2*)(L + swzA((r << 12) + (tid << 3)));

  // ---- mix(t0) over bits 9-11 ----
  regstage8(v, 1, c0, s0); regstage8(v, 2, c0, s0); regstage8(v, 4, c0, s0);

  if (MODE == 0) {
    float2* gdst = state + bb + lbase + tid;
#pragma unroll
    for (int r = 0; r < 8; ++r) gdst[r << 9] = v[r];
  } else if (MODE == 1) {
    const unsigned char* hq = hp8 + bb + lbase + tid;
    const float beta1 = betas[b * NLAYERS + t0 + 1];
    const float c1 = cosf(beta1), s1 = sinf(beta1);
#pragma unroll
    for (int r = 0; r < 8; ++r) pmul(v[r], ptab[hq[r << 9]]);
    // mix(t0+1) bits 9-11
    regstage8(v, 1, c1, s1); regstage8(v, 2, c1, s1); regstage8(v, 4, c1, s1);
    // swap back to partition1 (each thread rewrites the addrs it read: no sync needed first)
#pragma unroll
    for (int r = 0; r < 8; ++r)
      *(float2*)(L + swzA((r << 12) + (tid << 3))) = v[r];
    __syncthreads();
#pragma unroll
    for (int j = 0; j < 8; ++j)
      v[j] = *(const float2*)(L + swzA((tid << 6) + (j << 3)));
    // mix(t0+1) bits 0-8
    regstage8(v, 1, c1, s1); regstage8(v, 2, c1, s1); regstage8(v, 4, c1, s1);
    shflstage8(v, 1, c1, s1);  shflstage8(v, 2, c1, s1);  shflstage8(v, 4, c1, s1);
    shflstage8(v, 8, c1, s1);  shflstage8(v, 16, c1, s1); shflstage8(v, 32, c1, s1);
    float4* gdst = (float4*)(state + bb + lbase + (tid << 3));
#pragma unroll
    for (int j2 = 0; j2 < 4; ++j2)
      gdst[j2] = make_float4(v[2 * j2].x, v[2 * j2].y, v[2 * j2 + 1].x, v[2 * j2 + 1].y);
  } else {  // MODE 2: energy
    const unsigned char* hq = hp8 + bb + lbase + tid;
    float acc = 0.f;
#pragma unroll
    for (int r = 0; r < 8; ++r) {
      const float hr = (float)hq[r << 9];
      acc += (v[r].x * v[r].x + v[r].y * v[r].y) * hr;
    }
#pragma unroll
    for (int m = 1; m <= 32; m <<= 1) acc += __shfl_xor(acc, m, 64);
    if (lane == 0) wsum[w] = acc;
    __syncthreads();
    if (tid == 0) {
      float s = 0.f;
#pragma unroll
      for (int i = 0; i < 8; ++i) s += wsum[i];
      atomicAdd(out + b, s);
    }
  }
}

// ---------------- B-pass: mixes over element bits 12..17 -----------------
// Block: 512 threads, tile = 64 rows (bits 12-17) x 64 cols (bits 0-5),
// position mid = bits 6-11 = blockIdx&63.  lane = col (full coalescing).
// partition1: rows w<<3|j (reg j = bits 12-14); partition2: rows r<<3|w (reg r = bits 15-17)
// Does: mix(t0).high, phase, mix(t0+1).high
__global__ __launch_bounds__(512)
void k_high(const float* __restrict__ betas, const unsigned char* __restrict__ hp8,
            float2* __restrict__ state, int t0) {
  __shared__ float2 lds[4096];
  __shared__ float2 ptab[160];
  const int tid  = threadIdx.x;
  const int lane = tid & 63;
  const int w    = tid >> 6;
  if (tid < 160) {
    float s, c; sincosf((float)tid, &s, &c);
    ptab[tid] = make_float2(c, -s);
  }
  __syncthreads();
  const int b   = blockIdx.x >> 6;
  const int mid = blockIdx.x & 63;
  const size_t bb = (size_t)b << NQ;
  const int colbase = (mid << 6) | lane;

  const float beta0 = betas[b * NLAYERS + t0];
  const float c0 = cosf(beta0), s0 = sinf(beta0);
  const float beta1 = betas[b * NLAYERS + t0 + 1];
  const float c1 = cosf(beta1), s1 = sinf(beta1);

  float2 v[8];
#pragma unroll
  for (int j = 0; j < 8; ++j)
    v[j] = state[bb + ((size_t)((w << 3) | j) << 12) + colbase];

  // mix(t0) bits 12-14
  regstage8(v, 1, c0, s0); regstage8(v, 2, c0, s0); regstage8(v, 4, c0, s0);

  // swap to partition2
#pragma unroll
  for (int j = 0; j < 8; ++j)
    lds[(((w << 3) | j) << 6) | lane] = v[j];
  __syncthreads();
#pragma unroll
  for (int r = 0; r < 8; ++r)
    v[r] = lds[(((r << 3) | w) << 6) | lane];

  // mix(t0) bits 15-17
  regstage8(v, 1, c0, s0); regstage8(v, 2, c0, s0); regstage8(v, 4, c0, s0);

  // phase
#pragma unroll
  for (int r = 0; r < 8; ++r)
    pmul(v[r], ptab[hp8[bb + ((size_t)((r << 3) | w) << 12) + colbase]]);

  // mix(t0+1) bits 15-17
  regstage8(v, 1, c1, s1); regstage8(v, 2, c1, s1); regstage8(v, 4, c1, s1);

  // swap back to partition1
#pragma unroll
  for (int r = 0; r < 8; ++r)
    lds[(((r << 3) | w) << 6) | lane] = v[r];
  __syncthreads();
#pragma unroll
  for (int j = 0; j < 8; ++j)
    v[j] = lds[(((w << 3) | j) << 6) | lane];

  // mix(t0+1) bits 12-14
  regstage8(v, 1, c1, s1); regstage8(v, 2, c1, s1); regstage8(v, 4, c1, s1);

#pragma unroll
  for (int j = 0; j < 8; ++j)
    state[bb + ((size_t)((w << 3) | j) << 12) + colbase] = v[j];
}

extern "C" void kernel_launch(void* const* d_in, const int* in_sizes, int n_in,
                              void* d_out, int out_size, void* d_ws, size_t ws_size,
                              hipStream_t stream) {
  const float* betas = (const float*)d_in[0];  // [8][4]
  const float* adj   = (const float*)d_in[1];  // [8][18][18]
  float* out = (float*)d_out;                  // [8] float32
  char* ws = (char*)d_ws;
  float2* state = (float2*)ws;                                                        // 16 MB
  unsigned char* hp8 = (unsigned char*)(ws + (size_t)NBATCH * QDIM * sizeof(float2)); // 2 MB

  dim3 grid(512), blk(512);
  // P1: D + M1.low         P2: M1.high, D, M2.high
  // P3: M2.low, D, M3.low  P4: M3.high, D, M4.high
  // P5: M4.low + energy
  k_low<0><<<grid, blk, 0, stream>>>(betas, adj, hp8, state, out, 0);
  k_high<<<grid, blk, 0, stream>>>(betas, hp8, state, 0);
  k_low<1><<<grid, blk, 0, stream>>>(betas, adj, hp8, state, out, 1);
  k_high<<<grid, blk, 0, stream>>>(betas, hp8, state, 2);
  k_low<2><<<grid, blk, 0, stream>>>(betas, adj, hp8, state, out, 3);
}

// Round 4
// 66.706 us; speedup vs baseline: 1.6177x; 1.1594x over previous
//
#include <hip/hip_runtime.h>

#define NQ 18
#define QDIM (1 << NQ)      // 262144
#define NB 8
#define NL 4

typedef unsigned long long u64;

// tan-form butterfly: a' = a - i t b ; b' = b - i t a (cos^k deferred)
__device__ __forceinline__ void tbfly(float2& a, float2& b, float t) {
  float nax = fmaf(t, b.y, a.x);
  float nay = fmaf(-t, b.x, a.y);
  float nbx = fmaf(t, a.y, b.x);
  float nby = fmaf(-t, a.x, b.y);
  a = make_float2(nax, nay); b = make_float2(nbx, nby);
}
__device__ __forceinline__ void tstage(float2* v, int m, float t) {
#pragma unroll
  for (int i = 0; i < 16; ++i)
    if (!(i & m)) tbfly(v[i], v[i | m], t);
}
__device__ __forceinline__ void mix4(float2* v, float t) {
  tstage(v, 1, t); tstage(v, 2, t); tstage(v, 4, t); tstage(v, 8, t);
}
__device__ __forceinline__ void pmul(float2& a, float2 p) {
  a = make_float2(a.x * p.x - a.y * p.y, a.x * p.y + a.y * p.x);
}
// LDS swizzle: XOR 16B-granule index (byte bits 4-6) with bits 7-9. Involution;
// preserves 16B alignment so b128 and b64 both work through it.
__device__ __forceinline__ int swz(int byte) { return byte ^ (((byte >> 7) & 7) << 4); }

// ---------------- low pass: element bits 0..11 ----------------
// 256 thr, 16 elems/thread, tile = 4096 consecutive elems. Partitions:
//  p0: le = tid<<4 | j   (j = bits 0-3)
//  p1: le = hi4<<8 | j<<4 | lo4  (j = bits 4-7)
//  p2: le = j<<8 | tid   (j = bits 8-11)
// MODE 0: D+init (gray-code hp) at p0, mix(t0) p0->p1->p2, store
// MODE 1: load p2, mix(t0) p2->p1->p0, D at p0, mix(t1) p0->p1->p2, store
// MODE 2: load p2, mix(t3) p2->p1->p0, energy at p0 -> atomicAdd
template <int MODE>
__global__ __launch_bounds__(256)
void k_low(const float* __restrict__ betas, const float* __restrict__ adj,
           unsigned char* __restrict__ hp8, float2* __restrict__ state,
           float* __restrict__ out, int t0) {
  __shared__ float2 swapb[4096];   // 32 KB
  __shared__ float2 ptab[160];
  __shared__ unsigned smask[NQ];
  __shared__ unsigned sfull[4];
  __shared__ int sdeg[4];
  __shared__ float wsum[4];

  const int tid = threadIdx.x;
  const int b = blockIdx.x >> 6;
  const int blk6 = blockIdx.x & 63;
  const size_t bb = (size_t)b << NQ;
  const int lbase = blk6 << 12;
  const int hi4 = tid >> 4, lo4 = tid & 15;
  char* L = (char*)swapb;

  const float beta0 = betas[b * NL + t0];
  float s0, c0; sincosf(beta0, &s0, &c0);
  const float tf0 = s0 / c0;
  const float c0p2 = c0 * c0, c0p4 = c0p2 * c0p2;
  const float c0p12 = c0p4 * c0p4 * c0p4;

  float tf1 = 0.f, scale = 1.f;
  if (MODE == 0) scale = 0.001953125f * c0p12;   // 1/sqrt(2^18) * cos^12
  if (MODE == 1) {
    const float beta1 = betas[b * NL + t0 + 1];
    float s1, c1; sincosf(beta1, &s1, &c1);
    tf1 = s1 / c1;
    const float c1p2 = c1 * c1, c1p4 = c1p2 * c1p2;
    scale = c0p12 * (c1p4 * c1p4 * c1p4);
  }

  if (MODE == 0) {
    if (tid < NQ) {
      unsigned m = 0;
      const float* row = adj + ((size_t)b * NQ + tid) * NQ;
      for (int vq = tid + 1; vq < NQ; ++vq)
        if (row[vq] > 0.5f) m |= 1u << (NQ - 1 - vq);
      smask[tid] = m;
    }
    if (blk6 == 0 && tid == 0) out[b] = 0.f;
    __syncthreads();
    if (tid < 4) {  // full neighbor masks of the 4 low element bits (qubits 17-p)
      unsigned fm = smask[17 - tid];
      for (int uq = 0; uq < NQ; ++uq)
        if ((smask[uq] >> tid) & 1u) fm |= 1u << (17 - uq);
      sfull[tid] = fm; sdeg[tid] = __popc(fm);
    }
  }
  if (MODE != 2 && tid < 160) {
    float ss, cc; sincosf((float)tid, &ss, &cc);
    ptab[tid] = make_float2(cc * scale, -ss * scale);  // e^{-i h} * scale
  }

  float2 v[16];

  if (MODE == 0) {
    __syncthreads();
    // hp for 16 elems via gray code over element bits 0-3
    unsigned d = (unsigned)(lbase | (tid << 4));
    int hp = 0;
#pragma unroll
    for (int uq = 0; uq < NQ; ++uq) {
      const unsigned f = (d >> (17 - uq)) & 1u;
      hp += __popc(smask[uq] & (d ^ (0u - f)));
    }
    u64 plo = (u64)hp, phi = 0;
    int j = 0;
#pragma unroll
    for (int i = 1; i < 16; ++i) {
      const int p = __ffs(i) - 1;
      const unsigned fm = sfull[p];
      const int old = (int)((d >> p) & 1u);
      const int nb1 = __popc(fm & d);
      hp += old ? (2 * nb1 - sdeg[p]) : (sdeg[p] - 2 * nb1);
      d ^= 1u << p; j ^= 1 << p;
      if (j < 8) plo |= (u64)hp << (8 * j);
      else       phi |= (u64)hp << (8 * (j - 8));
    }
    uint4 hq;
    hq.x = (unsigned)plo; hq.y = (unsigned)(plo >> 32);
    hq.z = (unsigned)phi; hq.w = (unsigned)(phi >> 32);
    *(uint4*)(hp8 + bb + (size_t)(lbase + (tid << 4))) = hq;
#pragma unroll
    for (int jj = 0; jj < 16; ++jj) {
      const int h = (jj < 8) ? (int)((plo >> (8 * jj)) & 255)
                             : (int)((phi >> (8 * (jj - 8))) & 255);
      v[jj] = ptab[h];
    }
    // mix(t0): p0 -> p1 -> p2
    mix4(v, tf0);
#pragma unroll
    for (int q = 0; q < 8; ++q)
      *(float4*)(L + swz((tid << 7) + (q << 4))) =
          make_float4(v[2*q].x, v[2*q].y, v[2*q+1].x, v[2*q+1].y);
    __syncthreads();
#pragma unroll
    for (int jj = 0; jj < 16; ++jj)
      v[jj] = *(const float2*)(L + swz((hi4 << 11) + (jj << 7) + (lo4 << 3)));
    mix4(v, tf0);
#pragma unroll
    for (int jj = 0; jj < 16; ++jj)
      *(float2*)(L + swz((hi4 << 11) + (jj << 7) + (lo4 << 3))) = v[jj];
    __syncthreads();
#pragma unroll
    for (int jj = 0; jj < 16; ++jj)
      v[jj] = *(const float2*)(L + swz((jj << 11) + (tid << 3)));
    mix4(v, tf0);
#pragma unroll
    for (int jj = 0; jj < 16; ++jj)
      state[bb + (size_t)(lbase + (jj << 8) + tid)] = v[jj];
    return;
  }

  // MODE 1 / 2: load at p2, mix(t0) p2 -> p1 -> p0
#pragma unroll
  for (int jj = 0; jj < 16; ++jj)
    v[jj] = state[bb + (size_t)(lbase + (jj << 8) + tid)];
  mix4(v, tf0);                                   // bits 8-11
#pragma unroll
  for (int jj = 0; jj < 16; ++jj)
    *(float2*)(L + swz((jj << 11) + (tid << 3))) = v[jj];
  __syncthreads();
#pragma unroll
  for (int jj = 0; jj < 16; ++jj)
    v[jj] = *(const float2*)(L + swz((hi4 << 11) + (jj << 7) + (lo4 << 3)));
  mix4(v, tf0);                                   // bits 4-7
#pragma unroll
  for (int jj = 0; jj < 16; ++jj)
    *(float2*)(L + swz((hi4 << 11) + (jj << 7) + (lo4 << 3))) = v[jj];
  __syncthreads();
#pragma unroll
  for (int q = 0; q < 8; ++q) {
    const float4 f = *(const float4*)(L + swz((tid << 7) + (q << 4)));
    v[2*q]   = make_float2(f.x, f.y);
    v[2*q+1] = make_float2(f.z, f.w);
  }
  mix4(v, tf0);                                   // bits 0-3

  const uint4 hq = *(const uint4*)(hp8 + bb + (size_t)(lbase + (tid << 4)));

  if (MODE == 1) {
#pragma unroll
    for (int jj = 0; jj < 16; ++jj) {
      const unsigned word = (jj < 8) ? ((jj < 4) ? hq.x : hq.y)
                                     : ((jj < 12) ? hq.z : hq.w);
      const int h = (int)((word >> ((jj & 3) * 8)) & 255u);
      pmul(v[jj], ptab[h]);                       // phase * cos-scales
    }
    mix4(v, tf1);                                 // bits 0-3
#pragma unroll
    for (int q = 0; q < 8; ++q)
      *(float4*)(L + swz((tid << 7) + (q << 4))) =
          make_float4(v[2*q].x, v[2*q].y, v[2*q+1].x, v[2*q+1].y);
    __syncthreads();
#pragma unroll
    for (int jj = 0; jj < 16; ++jj)
      v[jj] = *(const float2*)(L + swz((hi4 << 11) + (jj << 7) + (lo4 << 3)));
    mix4(v, tf1);                                 // bits 4-7
#pragma unroll
    for (int jj = 0; jj < 16; ++jj)
      *(float2*)(L + swz((hi4 << 11) + (jj << 7) + (lo4 << 3))) = v[jj];
    __syncthreads();
#pragma unroll
    for (int jj = 0; jj < 16; ++jj)
      v[jj] = *(const float2*)(L + swz((jj << 11) + (tid << 3)));
    mix4(v, tf1);                                 // bits 8-11
#pragma unroll
    for (int jj = 0; jj < 16; ++jj)
      state[bb + (size_t)(lbase + (jj << 8) + tid)] = v[jj];
  } else {  // MODE 2: energy; scale BEFORE squaring (avoid overflow at big tan)
    float acc = 0.f;
#pragma unroll
    for (int jj = 0; jj < 16; ++jj) {
      const unsigned word = (jj < 8) ? ((jj < 4) ? hq.x : hq.y)
                                     : ((jj < 12) ? hq.z : hq.w);
      const float h = (float)((word >> ((jj & 3) * 8)) & 255u);
      const float wx = v[jj].x * c0p12, wy = v[jj].y * c0p12;
      acc = fmaf(wx * wx + wy * wy, h, acc);
    }
#pragma unroll
    for (int m = 1; m <= 32; m <<= 1) acc += __shfl_xor(acc, m, 64);
    if ((tid & 63) == 0) wsum[tid >> 6] = acc;
    __syncthreads();
    if (tid == 0) atomicAdd(out + b, wsum[0] + wsum[1] + wsum[2] + wsum[3]);
  }
}

// ---------------- high pass: element bits 12..17 ----------------
// 256 thr: w2 = tid>>6 (bits 16-17 at p0 / 12-13 at p1), lane = cols (bits 0-5),
// mid = blockIdx&63 (bits 6-11).  p0 rows = w2<<4|j (j = bits 12-15);
// p1 rows = j<<2|w2 (j = bits 14-17, stages on bits 16-17 = masks 4,8).
// [H_t0, D, H_t1]
__global__ __launch_bounds__(256)
void k_high(const float* __restrict__ betas, const unsigned char* __restrict__ hp8,
            float2* __restrict__ state, int t0) {
  __shared__ float2 swapb[4096];
  __shared__ float2 ptab[160];
  const int tid = threadIdx.x;
  const int w2 = tid >> 6, lane = tid & 63;
  const int b = blockIdx.x >> 6, mid = blockIdx.x & 63;
  const size_t bb = (size_t)b << NQ;
  const int base = (mid << 6) | lane;

  const float beta0 = betas[b * NL + t0], beta1 = betas[b * NL + t0 + 1];
  float s0, c0, s1, c1;
  sincosf(beta0, &s0, &c0); sincosf(beta1, &s1, &c1);
  const float tf0 = s0 / c0, tf1 = s1 / c1;
  const float c0p2 = c0 * c0, c1p2 = c1 * c1;
  const float scale = (c0p2 * c0p2 * c0p2) * (c1p2 * c1p2 * c1p2);  // cos^6 each
  if (tid < 160) {
    float ss, cc; sincosf((float)tid, &ss, &cc);
    ptab[tid] = make_float2(cc * scale, -ss * scale);
  }

  float2 v[16];
#pragma unroll
  for (int j = 0; j < 16; ++j)
    v[j] = state[bb + ((size_t)(((w2 << 4) | j)) << 12) + base];
  mix4(v, tf0);                                   // bits 12-15
#pragma unroll
  for (int j = 0; j < 16; ++j)
    swapb[((((w2 << 4) | j)) << 6) | lane] = v[j];
  __syncthreads();
#pragma unroll
  for (int j = 0; j < 16; ++j)
    v[j] = swapb[((((j << 2) | w2)) << 6) | lane];
  tstage(v, 4, tf0); tstage(v, 8, tf0);           // bits 16-17
#pragma unroll
  for (int j = 0; j < 16; ++j) {
    const int h = hp8[bb + ((size_t)(((j << 2) | w2)) << 12) + base];
    pmul(v[j], ptab[h]);
  }
  tstage(v, 4, tf1); tstage(v, 8, tf1);           // bits 16-17
#pragma unroll
  for (int j = 0; j < 16; ++j)
    swapb[((((j << 2) | w2)) << 6) | lane] = v[j];
  __syncthreads();
#pragma unroll
  for (int j = 0; j < 16; ++j)
    v[j] = swapb[((((w2 << 4) | j)) << 6) | lane];
  mix4(v, tf1);                                   // bits 12-15
#pragma unroll
  for (int j = 0; j < 16; ++j)
    state[bb + ((size_t)(((w2 << 4) | j)) << 12) + base] = v[j];
}

extern "C" void kernel_launch(void* const* d_in, const int* in_sizes, int n_in,
                              void* d_out, int out_size, void* d_ws, size_t ws_size,
                              hipStream_t stream) {
  const float* betas = (const float*)d_in[0];  // [8][4]
  const float* adj   = (const float*)d_in[1];  // [8][18][18]
  float* out = (float*)d_out;                  // [8] float32
  char* ws = (char*)d_ws;
  float2* state = (float2*)ws;                                              // 16 MB
  unsigned char* hp8 = (unsigned char*)(ws + (size_t)NB * QDIM * sizeof(float2));  // 2 MB

  dim3 grid(NB * 64), blk(256);
  // P1: D + L0      P2: H0 D H1      P3: L1 D L2      P4: H2 D H3      P5: L3 + E
  k_low<0><<<grid, blk, 0, stream>>>(betas, adj, hp8, state, out, 0);
  k_high  <<<grid, blk, 0, stream>>>(betas, hp8, state, 0);
  k_low<1><<<grid, blk, 0, stream>>>(betas, adj, hp8, state, out, 1);
  k_high  <<<grid, blk, 0, stream>>>(betas, hp8, state, 2);
  k_low<2><<<grid, blk, 0, stream>>>(betas, adj, hp8, state, out, 3);
}